// Round 4
// baseline (605.580 us; speedup 1.0000x reference)
//
#include <hip/hip_runtime.h>
#include <hip/hip_bf16.h>

// Problem constants (match reference setup_inputs()).
#define U_DIM 128
#define NUM_OUT_SEG 16
#define C_DIM 300
#define S_DIM 32
#define NUM_X0 10
#define P1 32
#define P2 64
#define P3 96
#define P_TOT (P1 + P2 + P3)
#define ONES_ROW 32          // extra LDS row of 1.0f — uniformizes all paths to degree 3
#define META_CAP 256         // 192 real + worst-case 16*3 pad < 256

typedef float vfloat2 __attribute__((ext_vector_type(2)));

// ---------------------------------------------------------------------------
// Prep kernel: bin the 192 paths by output segment o (16 bins), pad each bin
// to a multiple of 4 with dummy paths (c=0, idx=ONES_ROW^3).  All paths are
// emitted as degree-3: unused index slots point at the ones-row.
// ws layout: soff[17] ints at 0; meta[256] int4 at +256:
//            {w, idx0|idx1<<8|idx2<<16, c_bits, 0}
// ---------------------------------------------------------------------------
__global__ void prep_kernel(const int* __restrict__ idx1, const int* __restrict__ w1,
                            const int* __restrict__ o1, const float* __restrict__ c1,
                            const int* __restrict__ idx2, const int* __restrict__ w2,
                            const int* __restrict__ o2, const float* __restrict__ c2,
                            const int* __restrict__ idx3, const int* __restrict__ w3,
                            const int* __restrict__ o3, const float* __restrict__ c3,
                            int* __restrict__ soff, int4* __restrict__ meta) {
    __shared__ int cnt[NUM_OUT_SEG];
    __shared__ int off[NUM_OUT_SEG + 1];
    __shared__ int cur[NUM_OUT_SEG];
    const int t = threadIdx.x;
    if (t < NUM_OUT_SEG) cnt[t] = 0;
    // Pre-fill every meta slot with a dummy path (c = 0, ones-row indices).
    meta[t] = make_int4(0, ONES_ROW | (ONES_ROW << 8) | (ONES_ROW << 16), 0, 0);
    __syncthreads();

    int key = -1, w = 0, packed = 0;
    float c = 0.f;
    if (t < P_TOT) {
        int a0, a1 = ONES_ROW, a2 = ONES_ROW;
        if (t < P1) {
            int p = t;
            w = w1[p]; key = o1[p]; c = c1[p];
            a0 = idx1[p];
        } else if (t < P1 + P2) {
            int p = t - P1;
            w = w2[p]; key = o2[p]; c = c2[p];
            a0 = idx2[2 * p]; a1 = idx2[2 * p + 1];
        } else {
            int p = t - P1 - P2;
            w = w3[p]; key = o3[p]; c = c3[p];
            a0 = idx3[3 * p]; a1 = idx3[3 * p + 1]; a2 = idx3[3 * p + 2];
        }
        packed = a0 | (a1 << 8) | (a2 << 16);
        atomicAdd(&cnt[key], 1);
    }
    __syncthreads();
    if (t == 0) {
        int a = 0;
        for (int k = 0; k < NUM_OUT_SEG; ++k) {
            off[k] = a;
            a += (cnt[k] + 3) & ~3;  // pad each run to a multiple of 4
        }
        off[NUM_OUT_SEG] = a;
    }
    __syncthreads();
    if (t < NUM_OUT_SEG + 1) soff[t] = off[t];
    if (t < NUM_OUT_SEG) cur[t] = off[t];
    __syncthreads();
    if (t < P_TOT) {
        int r = atomicAdd(&cur[key], 1);
        meta[r] = make_int4(w, packed, __float_as_int(c), 0);
    }
}

// ---------------------------------------------------------------------------
// Main kernel: block = 512 threads = 8 waves = 1 batch row.
// Wave w owns output segments {2w, 2w+1}; its 64 lanes cover U=128 as float2.
// meta[p] is wave-uniform -> readfirstlane pushes path metadata into SGPRs
// (scalar addressing, cc as SGPR operand, no divergence).
// Inner loop: 4 paths per iteration (prep pads runs to x4) -> 4 independent
// load->FMA chains in flight.  All paths uniform degree-3 via the ones-row.
// LDS 16.9 KB -> 4 blocks/CU (wave cap) = 32 waves/CU if VGPR <= 64.
// ---------------------------------------------------------------------------
__global__ __launch_bounds__(512, 8) void contract_kernel(
    const float* __restrict__ x0, const int* __restrict__ i0,
    const float* __restrict__ x1, const int* __restrict__ soff,
    const int4* __restrict__ meta, float* __restrict__ out) {
    __shared__ vfloat2 x1s[(S_DIM + 1) * 64];  // 33 rows x 128 ch as float2

    const int tid = threadIdx.x;
    const int wave = tid >> 6;
    const int lane = tid & 63;
    const long b = blockIdx.x;

    // Stage x1 row (2048 float2, coalesced) + the ones-row.
    const vfloat2* x1p = (const vfloat2*)(x1 + b * (S_DIM * U_DIM));
#pragma unroll
    for (int k = 0; k < 4; ++k) {
        x1s[k * 512 + tid] = x1p[k * 512 + tid];
    }
    if (tid < 64) x1s[S_DIM * 64 + tid] = (vfloat2)(1.0f);

    const vfloat2* gbase = (const vfloat2*)x0 + (long)i0[b] * (C_DIM * 64);
    vfloat2* outb = (vfloat2*)(out + b * (NUM_OUT_SEG * U_DIM));
    __syncthreads();

#pragma unroll 1
    for (int oo = 0; oo < 2; ++oo) {
        const int o = wave * 2 + oo;
        vfloat2 acc = (vfloat2)(0.f);
        int p = soff[o];
        const int e = soff[o + 1];
#pragma unroll 1
        for (; p < e; p += 4) {
            int4 m0 = meta[p];
            int4 m1 = meta[p + 1];
            int4 m2 = meta[p + 2];
            int4 m3 = meta[p + 3];
            const int w0 = __builtin_amdgcn_readfirstlane(m0.x) << 6;
            const int y0 = __builtin_amdgcn_readfirstlane(m0.y);
            const float f0 = __uint_as_float((unsigned)__builtin_amdgcn_readfirstlane(m0.z));
            const int w1_ = __builtin_amdgcn_readfirstlane(m1.x) << 6;
            const int y1 = __builtin_amdgcn_readfirstlane(m1.y);
            const float f1 = __uint_as_float((unsigned)__builtin_amdgcn_readfirstlane(m1.z));
            const int w2_ = __builtin_amdgcn_readfirstlane(m2.x) << 6;
            const int y2 = __builtin_amdgcn_readfirstlane(m2.y);
            const float f2 = __uint_as_float((unsigned)__builtin_amdgcn_readfirstlane(m2.z));
            const int w3_ = __builtin_amdgcn_readfirstlane(m3.x) << 6;
            const int y3 = __builtin_amdgcn_readfirstlane(m3.y);
            const float f3 = __uint_as_float((unsigned)__builtin_amdgcn_readfirstlane(m3.z));

            vfloat2 ga = gbase[w0 + lane];
            vfloat2 gb = gbase[w1_ + lane];
            vfloat2 gc = gbase[w2_ + lane];
            vfloat2 gd = gbase[w3_ + lane];

            vfloat2 xa0 = x1s[((y0 & 255) << 6) + lane];
            vfloat2 xb0 = x1s[(((y0 >> 8) & 255) << 6) + lane];
            vfloat2 xc0 = x1s[(((y0 >> 16) & 255) << 6) + lane];
            vfloat2 xa1 = x1s[((y1 & 255) << 6) + lane];
            vfloat2 xb1 = x1s[(((y1 >> 8) & 255) << 6) + lane];
            vfloat2 xc1 = x1s[(((y1 >> 16) & 255) << 6) + lane];
            vfloat2 xa2 = x1s[((y2 & 255) << 6) + lane];
            vfloat2 xb2 = x1s[(((y2 >> 8) & 255) << 6) + lane];
            vfloat2 xc2 = x1s[(((y2 >> 16) & 255) << 6) + lane];
            vfloat2 xa3 = x1s[((y3 & 255) << 6) + lane];
            vfloat2 xb3 = x1s[(((y3 >> 8) & 255) << 6) + lane];
            vfloat2 xc3 = x1s[(((y3 >> 16) & 255) << 6) + lane];

            acc += (f0 * ga) * (xa0 * xb0 * xc0);
            acc += (f1 * gb) * (xa1 * xb1 * xc1);
            acc += (f2 * gc) * (xa2 * xb2 * xc2);
            acc += (f3 * gd) * (xa3 * xb3 * xc3);
        }
        // Streamed output, no reuse: keep it out of L2/L3.
        __builtin_nontemporal_store(acc, &outb[o * 64 + lane]);
    }
}

extern "C" void kernel_launch(void* const* d_in, const int* in_sizes, int n_in,
                              void* d_out, int out_size, void* d_ws, size_t ws_size,
                              hipStream_t stream) {
    const float* x0 = (const float*)d_in[0];
    const int* i0 = (const int*)d_in[1];
    const float* x1 = (const float*)d_in[2];
    const int* idx1 = (const int*)d_in[3];
    const int* w1 = (const int*)d_in[4];
    const int* o1 = (const int*)d_in[5];
    const float* c1 = (const float*)d_in[6];
    const int* idx2 = (const int*)d_in[7];
    const int* w2 = (const int*)d_in[8];
    const int* o2 = (const int*)d_in[9];
    const float* c2 = (const float*)d_in[10];
    const int* idx3 = (const int*)d_in[11];
    const int* w3 = (const int*)d_in[12];
    const int* o3 = (const int*)d_in[13];
    const float* c3 = (const float*)d_in[14];

    int* soff = (int*)d_ws;
    int4* meta = (int4*)((char*)d_ws + 256);

    const int B = in_sizes[1];  // 16384

    prep_kernel<<<1, META_CAP, 0, stream>>>(idx1, w1, o1, c1, idx2, w2, o2, c2,
                                            idx3, w3, o3, c3, soff, meta);
    contract_kernel<<<B, 512, 0, stream>>>(x0, i0, x1, soff, meta, (float*)d_out);
}

// Round 5
// 437.036 us; speedup vs baseline: 1.3857x; 1.3857x over previous
//
#include <hip/hip_runtime.h>
#include <hip/hip_bf16.h>

// Problem constants (match reference setup_inputs()).
#define U_DIM 128
#define NUM_OUT_SEG 16
#define C_DIM 300
#define S_DIM 32
#define NUM_X0 10
#define P1 32
#define P2 64
#define P3 96
#define P_TOT (P1 + P2 + P3)

typedef float vfloat4 __attribute__((ext_vector_type(4)));

// ---------------------------------------------------------------------------
// Prep kernel: counting-sort the 192 paths by key = o*3 + (deg-1) into 48
// contiguous runs.  Emits:
//   soff[49] ints at ws+0   (run boundaries; segment o spans [soff[3o],soff[3o+3]])
//   meta[192] int2 at ws+256: {w | s0<<9 | s1<<14 | s2<<19,  c_bits}
// Unused s-fields are 0 and never read (separate loop per degree).
// ---------------------------------------------------------------------------
__global__ void prep_kernel(const int* __restrict__ idx1, const int* __restrict__ w1,
                            const int* __restrict__ o1, const float* __restrict__ c1,
                            const int* __restrict__ idx2, const int* __restrict__ w2,
                            const int* __restrict__ o2, const float* __restrict__ c2,
                            const int* __restrict__ idx3, const int* __restrict__ w3,
                            const int* __restrict__ o3, const float* __restrict__ c3,
                            int* __restrict__ soff, int2* __restrict__ meta) {
    __shared__ int cnt[48];
    __shared__ int off[49];
    __shared__ int cur[48];
    const int t = threadIdx.x;
    if (t < 48) cnt[t] = 0;
    __syncthreads();

    int key = -1, packed = 0;
    float c = 0.f;
    if (t < P_TOT) {
        int deg, o, w, a0 = 0, a1 = 0, a2 = 0;
        if (t < P1) {
            int p = t;
            deg = 1; w = w1[p]; o = o1[p]; c = c1[p];
            a0 = idx1[p];
        } else if (t < P1 + P2) {
            int p = t - P1;
            deg = 2; w = w2[p]; o = o2[p]; c = c2[p];
            a0 = idx2[2 * p]; a1 = idx2[2 * p + 1];
        } else {
            int p = t - P1 - P2;
            deg = 3; w = w3[p]; o = o3[p]; c = c3[p];
            a0 = idx3[3 * p]; a1 = idx3[3 * p + 1]; a2 = idx3[3 * p + 2];
        }
        key = o * 3 + (deg - 1);
        packed = w | (a0 << 9) | (a1 << 14) | (a2 << 19);
        atomicAdd(&cnt[key], 1);
    }
    __syncthreads();
    if (t == 0) {
        int a = 0;
        for (int k = 0; k < 48; ++k) { off[k] = a; a += cnt[k]; }
        off[48] = a;
    }
    __syncthreads();
    if (t < 49) soff[t] = off[t];
    if (t < 48) cur[t] = off[t];
    __syncthreads();
    if (t < P_TOT) {
        int r = atomicAdd(&cur[key], 1);
        meta[r] = make_int2(packed, __float_as_int(c));
    }
}

// ---------------------------------------------------------------------------
// Main kernel: block = 1024 threads = 16 waves = 2 batch rows.
// Wave w owns output segment w for BOTH rows: lanes 0-31 = row 0, lanes
// 32-63 = row 1, float4 per lane (b128 LDS reads, amortized over 2 rows).
// Segment+degree runs are wave-uniform -> zero divergence; meta is a
// broadcast ds_read_b64 from LDS (no global chain, no readfirstlane).
// LDS 34 kB, launch_bounds(1024,8) -> 2 blocks/CU = 32 waves/CU = 100% occ.
// ---------------------------------------------------------------------------
__global__ __launch_bounds__(1024, 8) void contract_kernel(
    const float* __restrict__ x0, const int* __restrict__ i0,
    const float* __restrict__ x1, const int* __restrict__ soff,
    const int2* __restrict__ gmeta, float* __restrict__ out) {
    __shared__ vfloat4 x1s[2 * S_DIM * 32];  // [row][s][chunk], 32 kB
    __shared__ int2 smeta[P_TOT];            // 1.5 kB

    const int tid = threadIdx.x;
    const int wave = tid >> 6;   // output segment
    const int lane = tid & 63;
    const int h = lane >> 5;     // row within the pair
    const int ch = lane & 31;    // float4 chunk (covers U=128)
    const long b0 = (long)blockIdx.x * 2;

    // Stage 2 rows of x1 (2048 float4, coalesced 16B/lane) + meta copy.
    const vfloat4* x1p = (const vfloat4*)(x1 + b0 * (S_DIM * U_DIM));
    x1s[tid] = x1p[tid];
    x1s[tid + 1024] = x1p[tid + 1024];
    if (tid < P_TOT) smeta[tid] = gmeta[tid];

    const int elem = i0[b0 + h];
    const vfloat4* gseg = (const vfloat4*)x0 + (long)elem * (C_DIM * 32) + ch;
    const vfloat4* myx1 = x1s + h * (S_DIM * 32) + ch;

    int p = soff[wave * 3];
    const int e1 = soff[wave * 3 + 1];
    const int e2 = soff[wave * 3 + 2];
    const int e3 = soff[wave * 3 + 3];
    __syncthreads();

    vfloat4 acc = (vfloat4)(0.f);

    // degree-1 run
#pragma unroll 2
    for (; p < e1; ++p) {
        int2 m = smeta[p];
        float cc = __int_as_float(m.y);
        vfloat4 g = gseg[(m.x & 0x1FF) * 32];
        vfloat4 xa = myx1[((m.x >> 9) & 31) * 32];
        acc += (cc * g) * xa;
    }
    // degree-2 run
#pragma unroll 2
    for (; p < e2; ++p) {
        int2 m = smeta[p];
        float cc = __int_as_float(m.y);
        vfloat4 g = gseg[(m.x & 0x1FF) * 32];
        vfloat4 xa = myx1[((m.x >> 9) & 31) * 32];
        vfloat4 xb = myx1[((m.x >> 14) & 31) * 32];
        acc += (cc * g) * (xa * xb);
    }
    // degree-3 run
#pragma unroll 2
    for (; p < e3; ++p) {
        int2 m = smeta[p];
        float cc = __int_as_float(m.y);
        vfloat4 g = gseg[(m.x & 0x1FF) * 32];
        vfloat4 xa = myx1[((m.x >> 9) & 31) * 32];
        vfloat4 xb = myx1[((m.x >> 14) & 31) * 32];
        vfloat4 xc = myx1[((m.x >> 19) & 31) * 32];
        acc += (cc * g) * (xa * xb * xc);
    }

    // Streamed output (no reuse): nontemporal, coalesced 512B per half-wave.
    vfloat4* outp = (vfloat4*)(out + (b0 + h) * (NUM_OUT_SEG * U_DIM)) + wave * 32 + ch;
    __builtin_nontemporal_store(acc, outp);
}

extern "C" void kernel_launch(void* const* d_in, const int* in_sizes, int n_in,
                              void* d_out, int out_size, void* d_ws, size_t ws_size,
                              hipStream_t stream) {
    const float* x0 = (const float*)d_in[0];
    const int* i0 = (const int*)d_in[1];
    const float* x1 = (const float*)d_in[2];
    const int* idx1 = (const int*)d_in[3];
    const int* w1 = (const int*)d_in[4];
    const int* o1 = (const int*)d_in[5];
    const float* c1 = (const float*)d_in[6];
    const int* idx2 = (const int*)d_in[7];
    const int* w2 = (const int*)d_in[8];
    const int* o2 = (const int*)d_in[9];
    const float* c2 = (const float*)d_in[10];
    const int* idx3 = (const int*)d_in[11];
    const int* w3 = (const int*)d_in[12];
    const int* o3 = (const int*)d_in[13];
    const float* c3 = (const float*)d_in[14];

    int* soff = (int*)d_ws;
    int2* meta = (int2*)((char*)d_ws + 256);

    const int B = in_sizes[1];  // 16384

    prep_kernel<<<1, 256, 0, stream>>>(idx1, w1, o1, c1, idx2, w2, o2, c2,
                                       idx3, w3, o3, c3, soff, meta);
    contract_kernel<<<B / 2, 1024, 0, stream>>>(x0, i0, x1, soff, meta, (float*)d_out);
}